// Round 4
// baseline (528.910 us; speedup 1.0000x reference)
//
#include <hip/hip_runtime.h>
#include <math.h>

typedef _Float16 half8  __attribute__((ext_vector_type(8)));
typedef _Float16 half4v __attribute__((ext_vector_type(4)));
typedef float    f32x4  __attribute__((ext_vector_type(4)));

__device__ __forceinline__ _Float16 f2h(float f) { return (_Float16)f; }

#define LDSB (128 * 40)   // one 128x32 f16 tile, padded row stride 40

// C_part[zout][1024][ldc] (f16) = A[:, kb:kb+kLen] @ W[:, kb:kb+kLen]^T
// A: five 1024-wide f32 segments selected by global-k>>10.
// W: nsel=0 -> [W0 (k<w0cols, stride w0s) | W1 (stride w1s)], selected PER K-TILE;
//    nsel=1 -> W{0,1,2} selected by output-col block of 512 (each [512][1024]).
__device__ __forceinline__ void gemm_body(
    _Float16* __restrict__ sm,
    const float* A0, const float* A1, const float* A2p, const float* A3,
    const float* A4,
    const float* W0, const float* W1, const float* W2,
    int w0cols, int w0s, int w1s, int nsel,
    _Float16* __restrict__ Cpart, int ldc,
    int kb, int kLen, int ntile, int mtile, int zout)
{
    _Float16* smA = sm;             // [2][LDSB]
    _Float16* smW = sm + 2 * LDSB;  // [2][LDSB]
    const int tid  = threadIdx.x;
    const int lane = tid & 63;
    const int wid  = tid >> 6;
    const int wm   = wid >> 1, wn = wid & 1;
    const int m0   = mtile * 128;
    const int n0   = ntile * 128;
    const int nt   = kLen >> 5;
    const int srow = tid >> 3;         // 0..31
    const int scol = (tid & 7) << 2;   // 0..28
    const int fr   = lane & 15;
    const int kq   = lane >> 4;

    const float* wsel = nullptr;
    if (nsel) {
        int sel = n0 >> 9;
        const float* Wq = (sel == 0) ? W0 : (sel == 1) ? W1 : W2;
        wsel = Wq + (size_t)((n0 & 511) + srow) * 1024 + kb + scol;
    }

    f32x4 acc[4][4] = {};
    float4 va[4], vw[4];

    auto LOADA = [&](int lk) {
        int gk = kb + lk;
        int seg = gk >> 10;
        const float* ap = (seg == 0) ? A0 : (seg == 1) ? A1 : (seg == 2) ? A2p
                        : (seg == 3) ? A3 : A4;
        ap += (size_t)(m0 + srow) * 1024 + (gk & 1023) + scol;
        #pragma unroll
        for (int p = 0; p < 4; ++p)
            va[p] = *reinterpret_cast<const float4*>(ap + (size_t)p * 32 * 1024);
    };
    auto LOADW = [&](int lk) {
        const float* wp; int wstr;
        if (nsel) {
            wp = wsel + lk; wstr = 1024;
        } else {
            int gk = kb + lk;
            if (gk < w0cols) { wp = W0 + (size_t)(n0 + srow) * w0s + gk + scol;            wstr = w0s; }
            else             { wp = W1 + (size_t)(n0 + srow) * w1s + (gk - w0cols) + scol; wstr = w1s; }
        }
        #pragma unroll
        for (int p = 0; p < 4; ++p)
            vw[p] = *reinterpret_cast<const float4*>(wp + (size_t)p * 32 * wstr);
    };
    auto WRITEA = [&](int buf) {
        _Float16* d = smA + buf * LDSB;
        #pragma unroll
        for (int p = 0; p < 4; ++p) {
            half4v h = { f2h(va[p].x), f2h(va[p].y), f2h(va[p].z), f2h(va[p].w) };
            *reinterpret_cast<half4v*>(&d[(srow + p * 32) * 40 + scol]) = h;
        }
    };
    auto WRITEW = [&](int buf) {
        _Float16* d = smW + buf * LDSB;
        #pragma unroll
        for (int p = 0; p < 4; ++p) {
            half4v h = { f2h(vw[p].x), f2h(vw[p].y), f2h(vw[p].z), f2h(vw[p].w) };
            *reinterpret_cast<half4v*>(&d[(srow + p * 32) * 40 + scol]) = h;
        }
    };
    auto DOMFMA = [&](int buf) {
        half8 af[4], bf[4];
        _Float16* sA = smA + buf * LDSB;
        _Float16* sW = smW + buf * LDSB;
        #pragma unroll
        for (int i = 0; i < 4; ++i) {
            af[i] = *reinterpret_cast<const half8*>(&sA[(wm * 64 + i * 16 + fr) * 40 + kq * 8]);
            bf[i] = *reinterpret_cast<const half8*>(&sW[(wn * 64 + i * 16 + fr) * 40 + kq * 8]);
        }
        #pragma unroll
        for (int i = 0; i < 4; ++i)
            #pragma unroll
            for (int j = 0; j < 4; ++j)
                acc[i][j] = __builtin_amdgcn_mfma_f32_16x16x32_f16(af[i], bf[j], acc[i][j], 0, 0, 0);
    };

    LOADA(0); LOADW(0);
    WRITEA(0); WRITEW(0);
    __syncthreads();
    int cur = 0;
    for (int it = 0; it < nt - 1; ++it) {
        LOADA((it + 1) * 32);     // next-tile loads in flight under MFMA
        LOADW((it + 1) * 32);
        DOMFMA(cur);
        WRITEA(cur ^ 1);
        WRITEW(cur ^ 1);
        __syncthreads();
        cur ^= 1;
    }
    DOMFMA(cur);

    _Float16* cp = Cpart + (size_t)zout * 1024ull * (size_t)ldc;
    #pragma unroll
    for (int j = 0; j < 4; ++j) {
        int nc = n0 + wn * 64 + j * 16 + fr;
        #pragma unroll
        for (int i = 0; i < 4; ++i) {
            int rb = m0 + wm * 64 + i * 16 + kq * 4;
            #pragma unroll
            for (int r = 0; r < 4; ++r)
                cp[(size_t)(rb + r) * ldc + nc] = (_Float16)acc[i][j][r];
        }
    }
}

__device__ __forceinline__ void attend_body(
    char* smem,
    const float* __restrict__ feats,   // [B,L,1024]
    const float* __restrict__ pfeats,  // [B,L,512]
    const float* __restrict__ mask,    // [B,L]
    const _Float16* __restrict__ q0,   // [B,1536] partial z=0 (col-offset applied)
    const _Float16* __restrict__ q1,   // z=1
    const float* __restrict__ bq, const float* __restrict__ wa,
    const float* __restrict__ ba,
    float* __restrict__ outa, int L, int b)
{
    float* q   = (float*)smem;     // 512
    float* sc  = q + 512;          // 64
    float* wgt = sc + 64;          // 64
    const int tid = threadIdx.x;
    const int lane = tid & 63, wid = tid >> 6;
    for (int i = tid; i < 512; i += 256)
        q[i] = (float)q0[(size_t)b * 1536 + i] + (float)q1[(size_t)b * 1536 + i] + bq[i];
    __syncthreads();
    for (int l = wid; l < L; l += 4) {
        const float* pf = pfeats + ((size_t)b * L + l) * 512;
        float s = 0.f;
        #pragma unroll
        for (int h0 = 0; h0 < 512; h0 += 64) {
            int h = h0 + lane;
            s += tanhf(pf[h] + q[h]) * wa[h];
        }
        #pragma unroll
        for (int off = 32; off >= 1; off >>= 1) s += __shfl_xor(s, off);
        if (lane == 0) sc[l] = s + ba[0];
    }
    __syncthreads();
    if (tid < 64) {
        float v = (tid < L) ? sc[tid] : -1e30f;
        float m = v;
        #pragma unroll
        for (int off = 32; off >= 1; off >>= 1) m = fmaxf(m, __shfl_xor(m, off));
        float e = (tid < L) ? __expf(v - m) : 0.f;
        float sum = e;
        #pragma unroll
        for (int off = 32; off >= 1; off >>= 1) sum += __shfl_xor(sum, off);
        float w = e / sum;
        float wm = (tid < L) ? w * mask[(size_t)b * L + tid] : 0.f;
        float s2 = wm;
        #pragma unroll
        for (int off = 32; off >= 1; off >>= 1) s2 += __shfl_xor(s2, off);
        wgt[tid] = wm / (s2 + 1e-8f);
    }
    __syncthreads();
    const int d0 = tid * 4;
    float ax = 0.f, ay = 0.f, az = 0.f, aw = 0.f;
    for (int l = 0; l < L; ++l) {
        float w = wgt[l];
        const float4 v = *reinterpret_cast<const float4*>(feats + ((size_t)b * L + l) * 1024 + d0);
        ax += w * v.x; ay += w * v.y; az += w * v.z; aw += w * v.w;
    }
    float4 o; o.x = ax; o.y = ay; o.z = az; o.w = aw;
    *reinterpret_cast<float4*>(outa + (size_t)b * 1024 + d0) = o;
}

__global__ __launch_bounds__(256) void gemm_hf(
    const float* A0, const float* A1, const float* A2p, const float* A3,
    const float* A4,
    const float* W0, const float* W1, const float* W2,
    int w0cols, int w0s, int w1s, int nsel,
    _Float16* Cpart, int ldc, int kLen, int zbase)
{
    __shared__ _Float16 sm[4 * LDSB];
    gemm_body(sm, A0, A1, A2p, A3, A4, W0, W1, W2, w0cols, w0s, w1s, nsel,
              Cpart, ldc, blockIdx.z * kLen, kLen,
              blockIdx.x, blockIdx.y, zbase + blockIdx.z);
}

// blocks [0,gemmBlocks): lang-GEMM K-segs {h_att -> Wih cols 0-1023, h1 -> Whh};
// blocks [gemmBlocks, gemmBlocks+3072): the 3 attends.
__global__ __launch_bounds__(256) void fused_attend_gemm(
    const float* h_att, const float* h1,
    const float* lang_Wih, const float* lang_Whh, _Float16* g16,
    const float* attr_feats, const float* obj_feats, const float* rela_feats,
    const float* p_attr, const float* p_obj, const float* p_rela,
    const float* attr_masks, const float* att_masks, const float* rela_masks,
    const _Float16* q16,
    const float* attr_bq, const float* obj_bq, const float* rela_bq,
    const float* attr_wa, const float* obj_wa, const float* rela_wa,
    const float* attr_ba, const float* obj_ba, const float* rela_ba,
    float* a32, int gemmBlocks, int gkLen)
{
    __shared__ _Float16 sm[4 * LDSB];
    const int bid = blockIdx.x;
    if (bid < gemmBlocks) {
        const int z = bid >> 8, rem = bid & 255;
        gemm_body(sm, h_att, h1, h1, h1, h1,
                  lang_Wih, lang_Whh, lang_Whh, 1024, 4096, 1024, 0,
                  g16, 4096, z * gkLen, gkLen, rem & 31, rem >> 5, z);
    } else {
        const int ab = bid - gemmBlocks;
        const int mod = ab >> 10, b = ab & 1023;
        const float* feats  = (mod == 0) ? attr_feats : (mod == 1) ? obj_feats  : rela_feats;
        const float* pfeats = (mod == 0) ? p_attr     : (mod == 1) ? p_obj      : p_rela;
        const float* mask   = (mod == 0) ? attr_masks : (mod == 1) ? att_masks  : rela_masks;
        const float* bq     = (mod == 0) ? attr_bq    : (mod == 1) ? obj_bq     : rela_bq;
        const float* wa     = (mod == 0) ? attr_wa    : (mod == 1) ? obj_wa     : rela_wa;
        const float* ba     = (mod == 0) ? attr_ba    : (mod == 1) ? obj_ba     : rela_ba;
        const int L         = (mod == 0) ? 16 : (mod == 1) ? 36 : 64;
        attend_body((char*)sm, feats, pfeats, mask,
                    q16 + mod * 512, q16 + 1536ull * 1024 + mod * 512,
                    bq, wa, ba, a32 + (size_t)mod * 1024 * 1024, L, b);
    }
}

// LSTM elementwise from nz f16 gate partials + biases.
__global__ __launch_bounds__(256) void lstm4(
    const _Float16* __restrict__ g, size_t zstride, int nz,
    const float* __restrict__ bih, const float* __restrict__ bhh,
    const float* __restrict__ c_prev,
    float* __restrict__ hA, float* __restrict__ hB,
    float* __restrict__ c_out)
{
    int idx = blockIdx.x * 256 + threadIdx.x;  // [0, 1M)
    int b = idx >> 10, r = idx & 1023;
    size_t base = (size_t)b * 4096;
    float gi = bih[r]        + bhh[r];
    float gf = bih[1024 + r] + bhh[1024 + r];
    float gg = bih[2048 + r] + bhh[2048 + r];
    float go = bih[3072 + r] + bhh[3072 + r];
    for (int z = 0; z < nz; ++z) {
        const _Float16* gz = g + (size_t)z * zstride + base;
        gi += (float)gz[r];
        gf += (float)gz[1024 + r];
        gg += (float)gz[2048 + r];
        go += (float)gz[3072 + r];
    }
    float si = 1.f / (1.f + __expf(-gi));
    float sf = 1.f / (1.f + __expf(-gf));
    float so = 1.f / (1.f + __expf(-go));
    float c2 = sf * c_prev[idx] + si * tanhf(gg);
    float h2 = so * tanhf(c2);
    hA[idx] = h2;
    if (hB) hB[idx] = h2;
    c_out[idx] = c2;
}

extern "C" void kernel_launch(void* const* d_in, const int* in_sizes, int n_in,
                              void* d_out, int out_size, void* d_ws, size_t ws_size,
                              hipStream_t stream)
{
    const size_t BR = 1024ull * 1024ull;
    const float* xt         = (const float*)d_in[0];
    const float* fc         = (const float*)d_in[1];
    const float* state_h    = (const float*)d_in[2];
    const float* state_c    = (const float*)d_in[3];
    const float* attr_feats = (const float*)d_in[4];
    const float* obj_feats  = (const float*)d_in[5];
    const float* rela_feats = (const float*)d_in[6];
    const float* p_attr     = (const float*)d_in[7];
    const float* p_obj      = (const float*)d_in[8];
    const float* p_rela     = (const float*)d_in[9];
    const float* attr_masks = (const float*)d_in[10];
    const float* att_masks  = (const float*)d_in[11];
    const float* rela_masks = (const float*)d_in[12];
    const float* att_Wih    = (const float*)d_in[13];
    const float* att_Whh    = (const float*)d_in[14];
    const float* att_bih    = (const float*)d_in[15];
    const float* att_bhh    = (const float*)d_in[16];
    const float* lang_Wih   = (const float*)d_in[17];
    const float* lang_Whh   = (const float*)d_in[18];
    const float* lang_bih   = (const float*)d_in[19];
    const float* lang_bhh   = (const float*)d_in[20];
    const float* attr_Wq    = (const float*)d_in[21];
    const float* attr_bq    = (const float*)d_in[22];
    const float* attr_wa    = (const float*)d_in[23];
    const float* attr_ba    = (const float*)d_in[24];
    const float* obj_Wq     = (const float*)d_in[25];
    const float* obj_bq     = (const float*)d_in[26];
    const float* obj_wa     = (const float*)d_in[27];
    const float* obj_ba     = (const float*)d_in[28];
    const float* rela_Wq    = (const float*)d_in[29];
    const float* rela_bq    = (const float*)d_in[30];
    const float* rela_wa    = (const float*)d_in[31];
    const float* rela_ba    = (const float*)d_in[32];

    float* out = (float*)d_out;
    const float* h0 = state_h;            // state_h[0]
    const float* h1 = state_h + BR;       // state_h[1] (prev_h)
    float* h_att = out + BR;              // h_att output slot, reused as GEMM input

    // Workspace: primary (>=50MiB): 4 gate-partial slots; fallback: 2 slots (34MiB, R2-proven).
    const bool big = ws_size >= 52428800ull;
    const int gslots = big ? 4 : 2;
    _Float16* g16 = (_Float16*)d_ws;                         // [gslots][1024][4096] f16
    _Float16* q16 = g16 + (size_t)gslots * 4ull * BR;        // [2][1024][1536] f16
    float*    a32 = (float*)(q16 + 2ull * 1536 * 1024);      // [3][1024][1024] f32
    float* a_attr = a32;
    float* a_obj  = a32 + BR;
    float* a_rela = a32 + 2 * BR;

    dim3 blk(256);

    // 1) att-LSTM gates: A = [h1 | fc | xt | h0], K=4096 (Wih stride 3072, w0cols 3072)
    if (big)
        gemm_hf<<<dim3(32, 8, 4), blk, 0, stream>>>(
            h1, fc, xt, h0, h0, att_Wih, att_Whh, att_Whh,
            3072, 3072, 1024, 0, g16, 4096, 1024, 0);
    else
        gemm_hf<<<dim3(32, 8, 2), blk, 0, stream>>>(
            h1, fc, xt, h0, h0, att_Wih, att_Whh, att_Whh,
            3072, 3072, 1024, 0, g16, 4096, 2048, 0);
    // 2) att-LSTM elementwise -> h_att (out[BR]), c_att (out[3BR])
    lstm4<<<dim3(4096), blk, 0, stream>>>(
        g16, 4ull * BR, gslots, att_bih, att_bhh, state_c,
        h_att, nullptr, out + 3 * BR);
    // 3) fused q = h_att @ [Wq_attr;Wq_obj;Wq_rela]^T, N=1536, K=1024 split 2x512
    gemm_hf<<<dim3(12, 8, 2), blk, 0, stream>>>(
        h_att, h_att, h_att, h_att, h_att,
        attr_Wq, obj_Wq, rela_Wq, 0, 1024, 1024, 1,
        q16, 1536, 512, 0);
    // 4) fused: lang-GEMM segs {h_att, h1} + 3 attends
    {
        int gb = big ? 512 : 256;
        int gkLen = big ? 1024 : 2048;
        fused_attend_gemm<<<dim3(gb + 3072), blk, 0, stream>>>(
            h_att, h1, lang_Wih, lang_Whh, g16,
            attr_feats, obj_feats, rela_feats, p_attr, p_obj, p_rela,
            attr_masks, att_masks, rela_masks, q16,
            attr_bq, obj_bq, rela_bq, attr_wa, obj_wa, rela_wa,
            attr_ba, obj_ba, rela_ba, a32, gb, gkLen);
    }
    // 5) lang-GEMM late segs: A = [a_attr | a_obj | a_rela] vs Wih cols 1024-4095
    //    (W0 = lang_Wih + 1024, stride 4096, never crosses into W1)
    if (big)
        gemm_hf<<<dim3(32, 8, 2), blk, 0, stream>>>(
            a_attr, a_obj, a_rela, a_rela, a_rela,
            lang_Wih + 1024, lang_Wih, lang_Wih, 1 << 30, 4096, 4096, 0,
            g16, 4096, 1536, 2);
    else
        gemm_hf<<<dim3(32, 8, 1), blk, 0, stream>>>(
            a_attr, a_obj, a_rela, a_rela, a_rela,
            lang_Wih + 1024, lang_Wih, lang_Wih, 1 << 30, 4096, 4096, 0,
            g16, 4096, 3072, 1);
    // 6) lang-LSTM elementwise -> output (out[0]), h_lang (out[2BR]), c_lang (out[4BR])
    lstm4<<<dim3(4096), blk, 0, stream>>>(
        g16, 4ull * BR, gslots, lang_bih, lang_bhh, state_c + BR,
        out, out + 2 * BR, out + 4 * BR);
}

// Round 5
// 420.994 us; speedup vs baseline: 1.2563x; 1.2563x over previous
//
#include <hip/hip_runtime.h>
#include <math.h>

typedef _Float16 half8  __attribute__((ext_vector_type(8)));
typedef _Float16 half4v __attribute__((ext_vector_type(4)));
typedef float    f32x4  __attribute__((ext_vector_type(4)));

__device__ __forceinline__ _Float16 f2h(float f) { return (_Float16)f; }

__device__ __forceinline__ float tanh_fast(float x) {
    // 1 - 2/(e^{2x}+1); exact at +/-inf, ~1e-7 rel err. __expf -> v_exp.
    float e = __expf(2.f * x);
    return 1.f - 2.f / (e + 1.f);
}

#define LDSB (128 * 40)   // one 128x32 f16 tile, padded row stride 40

// C_part[zout][1024][ldc] (f16) = A[:, kb:kb+kLen] @ W[:, kb:kb+kLen]^T
// A: five 1024-wide f32 segments selected by global-k>>10.
// W: nsel=0 -> [W0 (k<w0cols, stride w0s) | W1 (stride w1s)], selected PER K-TILE;
//    nsel=1 -> W{0,1,2} selected by output-col block of 512 (each [512][1024]).
__device__ __forceinline__ void gemm_body(
    _Float16* __restrict__ sm,
    const float* A0, const float* A1, const float* A2p, const float* A3,
    const float* A4,
    const float* W0, const float* W1, const float* W2,
    int w0cols, int w0s, int w1s, int nsel,
    _Float16* __restrict__ Cpart, int ldc,
    int kb, int kLen, int ntile, int mtile, int zout)
{
    _Float16* smA = sm;             // [2][LDSB]
    _Float16* smW = sm + 2 * LDSB;  // [2][LDSB]
    const int tid  = threadIdx.x;
    const int lane = tid & 63;
    const int wid  = tid >> 6;
    const int wm   = wid >> 1, wn = wid & 1;
    const int m0   = mtile * 128;
    const int n0   = ntile * 128;
    const int nt   = kLen >> 5;
    const int srow = tid >> 3;         // 0..31
    const int scol = (tid & 7) << 2;   // 0..28
    const int fr   = lane & 15;
    const int kq   = lane >> 4;

    const float* wsel = nullptr;
    if (nsel) {
        int sel = n0 >> 9;
        const float* Wq = (sel == 0) ? W0 : (sel == 1) ? W1 : W2;
        wsel = Wq + (size_t)((n0 & 511) + srow) * 1024 + kb + scol;
    }

    f32x4 acc[4][4] = {};
    float4 va[4], vw[4];

    auto LOADA = [&](int lk) {
        int gk = kb + lk;
        int seg = gk >> 10;
        const float* ap = (seg == 0) ? A0 : (seg == 1) ? A1 : (seg == 2) ? A2p
                        : (seg == 3) ? A3 : A4;
        ap += (size_t)(m0 + srow) * 1024 + (gk & 1023) + scol;
        #pragma unroll
        for (int p = 0; p < 4; ++p)
            va[p] = *reinterpret_cast<const float4*>(ap + (size_t)p * 32 * 1024);
    };
    auto LOADW = [&](int lk) {
        const float* wp; int wstr;
        if (nsel) {
            wp = wsel + lk; wstr = 1024;
        } else {
            int gk = kb + lk;
            if (gk < w0cols) { wp = W0 + (size_t)(n0 + srow) * w0s + gk + scol;            wstr = w0s; }
            else             { wp = W1 + (size_t)(n0 + srow) * w1s + (gk - w0cols) + scol; wstr = w1s; }
        }
        #pragma unroll
        for (int p = 0; p < 4; ++p)
            vw[p] = *reinterpret_cast<const float4*>(wp + (size_t)p * 32 * wstr);
    };
    auto WRITEA = [&](int buf) {
        _Float16* d = smA + buf * LDSB;
        #pragma unroll
        for (int p = 0; p < 4; ++p) {
            half4v h = { f2h(va[p].x), f2h(va[p].y), f2h(va[p].z), f2h(va[p].w) };
            *reinterpret_cast<half4v*>(&d[(srow + p * 32) * 40 + scol]) = h;
        }
    };
    auto WRITEW = [&](int buf) {
        _Float16* d = smW + buf * LDSB;
        #pragma unroll
        for (int p = 0; p < 4; ++p) {
            half4v h = { f2h(vw[p].x), f2h(vw[p].y), f2h(vw[p].z), f2h(vw[p].w) };
            *reinterpret_cast<half4v*>(&d[(srow + p * 32) * 40 + scol]) = h;
        }
    };
    auto DOMFMA = [&](int buf) {
        half8 af[4], bf[4];
        _Float16* sA = smA + buf * LDSB;
        _Float16* sW = smW + buf * LDSB;
        #pragma unroll
        for (int i = 0; i < 4; ++i) {
            af[i] = *reinterpret_cast<const half8*>(&sA[(wm * 64 + i * 16 + fr) * 40 + kq * 8]);
            bf[i] = *reinterpret_cast<const half8*>(&sW[(wn * 64 + i * 16 + fr) * 40 + kq * 8]);
        }
        #pragma unroll
        for (int i = 0; i < 4; ++i)
            #pragma unroll
            for (int j = 0; j < 4; ++j)
                acc[i][j] = __builtin_amdgcn_mfma_f32_16x16x32_f16(af[i], bf[j], acc[i][j], 0, 0, 0);
    };

    LOADA(0); LOADW(0);
    WRITEA(0); WRITEW(0);
    __syncthreads();
    int cur = 0;
    for (int it = 0; it < nt - 1; ++it) {
        LOADA((it + 1) * 32);     // next-tile loads in flight under MFMA
        LOADW((it + 1) * 32);
        DOMFMA(cur);
        WRITEA(cur ^ 1);
        WRITEW(cur ^ 1);
        __syncthreads();
        cur ^= 1;
    }
    DOMFMA(cur);

    _Float16* cp = Cpart + (size_t)zout * 1024ull * (size_t)ldc;
    #pragma unroll
    for (int j = 0; j < 4; ++j) {
        int nc = n0 + wn * 64 + j * 16 + fr;
        #pragma unroll
        for (int i = 0; i < 4; ++i) {
            int rb = m0 + wm * 64 + i * 16 + kq * 4;
            #pragma unroll
            for (int r = 0; r < 4; ++r)
                cp[(size_t)(rb + r) * ldc + nc] = (_Float16)acc[i][j][r];
        }
    }
}

__global__ __launch_bounds__(256) void gemm_hf(
    const float* A0, const float* A1, const float* A2p, const float* A3,
    const float* A4,
    const float* W0, const float* W1, const float* W2,
    int w0cols, int w0s, int w1s, int nsel,
    _Float16* Cpart, int ldc, int kLen, int zbase)
{
    __shared__ _Float16 sm[4 * LDSB];
    gemm_body(sm, A0, A1, A2p, A3, A4, W0, W1, W2, w0cols, w0s, w1s, nsel,
              Cpart, ldc, blockIdx.z * kLen, kLen,
              blockIdx.x, blockIdx.y, zbase + blockIdx.z);
}

// Standalone attend: grid (B, 3) -> (batch row, modality). Small LDS (high occupancy).
__global__ __launch_bounds__(256) void attend3(
    const float* __restrict__ attr_feats, const float* __restrict__ obj_feats,
    const float* __restrict__ rela_feats,
    const float* __restrict__ p_attr, const float* __restrict__ p_obj,
    const float* __restrict__ p_rela,
    const float* __restrict__ attr_masks, const float* __restrict__ att_masks,
    const float* __restrict__ rela_masks,
    const _Float16* __restrict__ q16,   // [2][B][1536]
    const float* __restrict__ attr_bq, const float* __restrict__ obj_bq,
    const float* __restrict__ rela_bq,
    const float* __restrict__ attr_wa, const float* __restrict__ obj_wa,
    const float* __restrict__ rela_wa,
    const float* __restrict__ attr_ba, const float* __restrict__ obj_ba,
    const float* __restrict__ rela_ba,
    float* __restrict__ a32)            // [3][B][1024]
{
    __shared__ float q[512];
    __shared__ float sc[64];
    __shared__ float wgt[64];
    const int b   = blockIdx.x;
    const int mod = blockIdx.y;
    const float* feats  = (mod == 0) ? attr_feats : (mod == 1) ? obj_feats  : rela_feats;
    const float* pfeats = (mod == 0) ? p_attr     : (mod == 1) ? p_obj      : p_rela;
    const float* mask   = (mod == 0) ? attr_masks : (mod == 1) ? att_masks  : rela_masks;
    const float* bq     = (mod == 0) ? attr_bq    : (mod == 1) ? obj_bq     : rela_bq;
    const float* wa     = (mod == 0) ? attr_wa    : (mod == 1) ? obj_wa     : rela_wa;
    const float* ba     = (mod == 0) ? attr_ba    : (mod == 1) ? obj_ba     : rela_ba;
    const int L         = (mod == 0) ? 16 : (mod == 1) ? 36 : 64;
    float* outa = a32 + (size_t)mod * 1024 * 1024;

    const int tid = threadIdx.x;
    const int lane = tid & 63, wid = tid >> 6;
    const _Float16* q0 = q16 + mod * 512;
    const _Float16* q1 = q16 + 1536ull * 1024 + mod * 512;
    for (int i = tid; i < 512; i += 256)
        q[i] = (float)q0[(size_t)b * 1536 + i] + (float)q1[(size_t)b * 1536 + i] + bq[i];
    __syncthreads();
    for (int l = wid; l < L; l += 4) {
        const float* pf = pfeats + ((size_t)b * L + l) * 512;
        float s = 0.f;
        #pragma unroll
        for (int h0 = 0; h0 < 512; h0 += 64) {
            int h = h0 + lane;
            s += tanh_fast(pf[h] + q[h]) * wa[h];
        }
        #pragma unroll
        for (int off = 32; off >= 1; off >>= 1) s += __shfl_xor(s, off);
        if (lane == 0) sc[l] = s + ba[0];
    }
    __syncthreads();
    if (tid < 64) {
        float v = (tid < L) ? sc[tid] : -1e30f;
        float m = v;
        #pragma unroll
        for (int off = 32; off >= 1; off >>= 1) m = fmaxf(m, __shfl_xor(m, off));
        float e = (tid < L) ? __expf(v - m) : 0.f;
        float sum = e;
        #pragma unroll
        for (int off = 32; off >= 1; off >>= 1) sum += __shfl_xor(sum, off);
        float w = e / sum;
        float wm = (tid < L) ? w * mask[(size_t)b * L + tid] : 0.f;
        float s2 = wm;
        #pragma unroll
        for (int off = 32; off >= 1; off >>= 1) s2 += __shfl_xor(s2, off);
        wgt[tid] = wm / (s2 + 1e-8f);
    }
    __syncthreads();
    const int d0 = tid * 4;
    float ax = 0.f, ay = 0.f, az = 0.f, aw = 0.f;
    for (int l = 0; l < L; ++l) {
        float w = wgt[l];
        const float4 v = *reinterpret_cast<const float4*>(feats + ((size_t)b * L + l) * 1024 + d0);
        ax += w * v.x; ay += w * v.y; az += w * v.z; aw += w * v.w;
    }
    float4 o; o.x = ax; o.y = ay; o.z = az; o.w = aw;
    *reinterpret_cast<float4*>(outa + (size_t)b * 1024 + d0) = o;
}

// LSTM elementwise from nz f16 gate partials + biases.
__global__ __launch_bounds__(256) void lstm4(
    const _Float16* __restrict__ g, size_t zstride, int nz,
    const float* __restrict__ bih, const float* __restrict__ bhh,
    const float* __restrict__ c_prev,
    float* __restrict__ hA, float* __restrict__ hB,
    float* __restrict__ c_out)
{
    int idx = blockIdx.x * 256 + threadIdx.x;  // [0, 1M)
    int b = idx >> 10, r = idx & 1023;
    size_t base = (size_t)b * 4096;
    float gi = bih[r]        + bhh[r];
    float gf = bih[1024 + r] + bhh[1024 + r];
    float gg = bih[2048 + r] + bhh[2048 + r];
    float go = bih[3072 + r] + bhh[3072 + r];
    for (int z = 0; z < nz; ++z) {
        const _Float16* gz = g + (size_t)z * zstride + base;
        gi += (float)gz[r];
        gf += (float)gz[1024 + r];
        gg += (float)gz[2048 + r];
        go += (float)gz[3072 + r];
    }
    float si = 1.f / (1.f + __expf(-gi));
    float sf = 1.f / (1.f + __expf(-gf));
    float so = 1.f / (1.f + __expf(-go));
    float c2 = sf * c_prev[idx] + si * tanh_fast(gg);
    float h2 = so * tanh_fast(c2);
    hA[idx] = h2;
    if (hB) hB[idx] = h2;
    c_out[idx] = c2;
}

extern "C" void kernel_launch(void* const* d_in, const int* in_sizes, int n_in,
                              void* d_out, int out_size, void* d_ws, size_t ws_size,
                              hipStream_t stream)
{
    const size_t BR = 1024ull * 1024ull;
    const float* xt         = (const float*)d_in[0];
    const float* fc         = (const float*)d_in[1];
    const float* state_h    = (const float*)d_in[2];
    const float* state_c    = (const float*)d_in[3];
    const float* attr_feats = (const float*)d_in[4];
    const float* obj_feats  = (const float*)d_in[5];
    const float* rela_feats = (const float*)d_in[6];
    const float* p_attr     = (const float*)d_in[7];
    const float* p_obj      = (const float*)d_in[8];
    const float* p_rela     = (const float*)d_in[9];
    const float* attr_masks = (const float*)d_in[10];
    const float* att_masks  = (const float*)d_in[11];
    const float* rela_masks = (const float*)d_in[12];
    const float* att_Wih    = (const float*)d_in[13];
    const float* att_Whh    = (const float*)d_in[14];
    const float* att_bih    = (const float*)d_in[15];
    const float* att_bhh    = (const float*)d_in[16];
    const float* lang_Wih   = (const float*)d_in[17];
    const float* lang_Whh   = (const float*)d_in[18];
    const float* lang_bih   = (const float*)d_in[19];
    const float* lang_bhh   = (const float*)d_in[20];
    const float* attr_Wq    = (const float*)d_in[21];
    const float* attr_bq    = (const float*)d_in[22];
    const float* attr_wa    = (const float*)d_in[23];
    const float* attr_ba    = (const float*)d_in[24];
    const float* obj_Wq     = (const float*)d_in[25];
    const float* obj_bq     = (const float*)d_in[26];
    const float* obj_wa     = (const float*)d_in[27];
    const float* obj_ba     = (const float*)d_in[28];
    const float* rela_Wq    = (const float*)d_in[29];
    const float* rela_bq    = (const float*)d_in[30];
    const float* rela_wa    = (const float*)d_in[31];
    const float* rela_ba    = (const float*)d_in[32];

    float* out = (float*)d_out;
    const float* h0 = state_h;            // state_h[0]
    const float* h1 = state_h + BR;       // state_h[1] (prev_h)
    float* h_att = out + BR;              // h_att output slot, reused as GEMM input

    // Workspace: primary (>=50MiB): 4 gate-partial slots; fallback: 2 slots (34MiB, proven).
    const bool big = ws_size >= 52428800ull;
    const int gslots = big ? 4 : 2;
    _Float16* g16 = (_Float16*)d_ws;                         // [gslots][1024][4096] f16
    _Float16* q16 = g16 + (size_t)gslots * 4ull * BR;        // [2][1024][1536] f16
    float*    a32 = (float*)(q16 + 2ull * 1536 * 1024);      // [3][1024][1024] f32
    float* a_attr = a32;
    float* a_obj  = a32 + BR;
    float* a_rela = a32 + 2 * BR;

    dim3 blk(256);
    const int zsplit = big ? 4 : 2;

    // 1) att-LSTM gates: A = [h1 | fc | xt | h0], K=4096 (Wih 3072 cols, then Whh)
    gemm_hf<<<dim3(32, 8, zsplit), blk, 0, stream>>>(
        h1, fc, xt, h0, h0, att_Wih, att_Whh, att_Whh,
        3072, 3072, 1024, 0, g16, 4096, 4096 / zsplit, 0);
    // 2) att-LSTM elementwise -> h_att (out[BR]), c_att (out[3BR])
    lstm4<<<dim3(4096), blk, 0, stream>>>(
        g16, 4ull * BR, gslots, att_bih, att_bhh, state_c,
        h_att, nullptr, out + 3 * BR);
    // 3) fused q = h_att @ [Wq_attr;Wq_obj;Wq_rela]^T, N=1536, K=1024 split 2x512
    gemm_hf<<<dim3(12, 8, 2), blk, 0, stream>>>(
        h_att, h_att, h_att, h_att, h_att,
        attr_Wq, obj_Wq, rela_Wq, 0, 1024, 1024, 1,
        q16, 1536, 512, 0);
    // 4) attends (standalone, 2.5KB LDS -> 8 blocks/CU)
    attend3<<<dim3(1024, 3), blk, 0, stream>>>(
        attr_feats, obj_feats, rela_feats, p_attr, p_obj, p_rela,
        attr_masks, att_masks, rela_masks, q16,
        attr_bq, obj_bq, rela_bq, attr_wa, obj_wa, rela_wa,
        attr_ba, obj_ba, rela_ba, a32);
    // 5) lang-LSTM gates: A = [h_att | a_attr | a_obj | a_rela | h1], K=5120,
    //    one kernel, split-K 4 (kLen=1280; k-tiles never straddle 1024 boundaries)
    gemm_hf<<<dim3(32, 8, zsplit), blk, 0, stream>>>(
        h_att, a_attr, a_obj, a_rela, h1,
        lang_Wih, lang_Whh, lang_Whh, 4096, 4096, 1024, 0,
        g16, 4096, 5120 / zsplit, 0);
    // 6) lang-LSTM elementwise -> output (out[0]), h_lang (out[2BR]), c_lang (out[4BR])
    lstm4<<<dim3(4096), blk, 0, stream>>>(
        g16, 4ull * BR, gslots, lang_bih, lang_bhh, state_c + BR,
        out, out + 2 * BR, out + 4 * BR);
}